// Round 6
// baseline (321.410 us; speedup 1.0000x reference)
//
#include <hip/hip_runtime.h>

// relative_depth_crit — R5: stripe-LDS gather restructure.
// R1-R4 proved a hard ~4.2 cyc/lane per-CU cap on scattered global gathers
// (insensitive to MLP, occupancy, L1 bypass, LDS-DMA). Fix: gather from LDS
// instead. Block = 1/4 batch (25000 pts in registers, 512thr x 49pts);
// 11 stripes of 48 rows as bf16 in 61KB LDS; predicated ds_read_u16 resolves
// points per stripe. 4 sibling blocks per batch share stripes via XCD L2.

constexpr int B = 64;
constexpr int H = 512;
constexpr int W = 640;
constexpr int P = 100000;
constexpr int SEGS = 4;                     // blocks per batch
constexpr int SEGP = P / SEGS;              // 25000 points per block
constexpr int NT = 512;                     // threads per block
constexpr int K = (SEGP + NT - 1) / NT;     // 49 points per thread
constexpr int TAIL_T = SEGP - (K - 1) * NT; // 424: valid threads at k=K-1
constexpr int SROWS = 48;                   // stripe rows (bf16 -> 61440 B LDS)
constexpr int NS = (H + SROWS - 1) / SROWS; // 11 stripes
constexpr int SELEMS = SROWS * W;           // 30720 elements per full stripe
constexpr int NBLK = B * SEGS;              // 256 blocks = 1 per CU
constexpr float INV_N = 1.0f / (float)(B * P);

typedef float vfloat4 __attribute__((ext_vector_type(4)));

__global__ __launch_bounds__(NT, 2) void rdc_kernel(
        const float* __restrict__ depth,
        const int* __restrict__ xA, const int* __restrict__ yA,
        const int* __restrict__ xB, const int* __restrict__ yB,
        const int* __restrict__ ord,
        float* __restrict__ partials) {
    __shared__ unsigned short stripe[SELEMS];   // 61440 B
    __shared__ float wsum[8];

    int j = blockIdx.x;
    // XCD swizzle: x = j&7 ~ XCD. All 4 segs of a batch on one XCD, adjacent
    // in dispatch order -> lockstep stripe sharing through that XCD's L2.
    int x = j & 7;
    int g = j >> 3;                  // 0..31
    int b = (g >> 2) * 8 + x;        // batch 0..63
    int c = g & 3;                   // segment 0..3
    int t = threadIdx.x;

    const float* slab = depth + (size_t)b * (H * W);
    int base_pt = b * P + c * SEGP;  // global point index base

    // ---- phase 1: load this thread's 49 points into registers ----
    int offA[K], offB[K];
    float zA[K], zB[K];
    unsigned rankW[2] = {0u, 0u};    // bit k: ordinal != 1 (ranking term)
    unsigned signW[2] = {0u, 0u};    // bit k: ordinal == 2 (gt = +1)
    #pragma unroll
    for (int k = 0; k < K; ++k) {
        int pl = k * NT + t;
        if (k == K - 1 && pl >= SEGP) pl = SEGP - 1;   // clamp tail (masked later)
        int gi = base_pt + pl;
        int xa = __builtin_nontemporal_load(&xA[gi]);
        int ya = __builtin_nontemporal_load(&yA[gi]);
        int xb = __builtin_nontemporal_load(&xB[gi]);
        int yb = __builtin_nontemporal_load(&yB[gi]);
        int od = __builtin_nontemporal_load(&ord[gi]);
        offA[k] = ya * W + xa;
        offB[k] = yb * W + xb;
        rankW[k >> 5] |= (unsigned)(od != 1) << (k & 31);
        signW[k >> 5] |= (unsigned)(od == 2) << (k & 31);
        zA[k] = 0.0f;
        zB[k] = 0.0f;
    }

    // ---- phase 2: stripe loop — stream slab stripe to LDS (bf16), gather ----
    for (int s = 0; s < NS; ++s) {
        int base = s * SELEMS;                       // first slab element of stripe
        int rows = (s == NS - 1) ? (H - s * SROWS) : SROWS;
        unsigned span = (unsigned)(rows * W);        // elements in this stripe
        int nv4 = (int)(span >> 2);                  // float4 count

        __syncthreads();   // everyone done gathering from previous stripe
        // cooperative load: float4 from slab -> round-half-up bf16 -> LDS
        for (int i4 = t; i4 < nv4; i4 += NT) {
            vfloat4 v = *(const vfloat4*)(slab + base + (i4 << 2));
            unsigned u0 = (__builtin_bit_cast(unsigned, v.x) + 0x8000u) >> 16;
            unsigned u1 = (__builtin_bit_cast(unsigned, v.y) + 0x8000u) >> 16;
            unsigned u2 = (__builtin_bit_cast(unsigned, v.z) + 0x8000u) >> 16;
            unsigned u3 = (__builtin_bit_cast(unsigned, v.w) + 0x8000u) >> 16;
            uint2 pk;
            pk.x = u0 | (u1 << 16);
            pk.y = u2 | (u3 << 16);
            *(uint2*)&stripe[i4 << 2] = pk;
        }
        __syncthreads();   // stripe visible

        #pragma unroll
        for (int k = 0; k < K; ++k) {
            unsigned la = (unsigned)(offA[k] - base);
            if (la < span)
                zA[k] = __builtin_bit_cast(float, (unsigned)stripe[la] << 16);
            unsigned lb = (unsigned)(offB[k] - base);
            if (lb < span)
                zB[k] = __builtin_bit_cast(float, (unsigned)stripe[lb] << 16);
        }
    }

    // ---- phase 3: loss ----
    float tailf = (t < TAIL_T) ? 1.0f : 0.0f;
    float acc = 0.0f;
    #pragma unroll
    for (int k = 0; k < K; ++k) {
        float zd = zA[k] - zB[k];
        unsigned rb = (rankW[k >> 5] >> (k & 31)) & 1u;
        unsigned sb = (signW[k >> 5] >> (k & 31)) & 1u;
        float gt = sb ? 1.0f : -1.0f;
        float lr = __logf(1.0f + __expf(-fminf(gt * zd, 1.0f)));
        float le = fmaxf(zd * zd, 1.0f);
        float l = rb ? lr : le;
        if (k == K - 1) l *= tailf;
        acc += l;
    }

    // ---- phase 4: reduction (8 waves) ----
    #pragma unroll
    for (int o = 32; o > 0; o >>= 1)
        acc += __shfl_down(acc, o, 64);
    int lane = t & 63;
    int wid  = t >> 6;
    if (lane == 0) wsum[wid] = acc;
    __syncthreads();
    if (wid == 0 && lane == 0) {
        float v = 0.0f;
        #pragma unroll
        for (int w = 0; w < 8; ++w) v += wsum[w];
        partials[j] = v;
    }
}

__global__ __launch_bounds__(256) void rdc_finalize(
        const float* __restrict__ partials, float* __restrict__ out, int n) {
    float acc = 0.0f;
    for (int k = threadIdx.x; k < n; k += 256)
        acc += partials[k];
    #pragma unroll
    for (int o = 32; o > 0; o >>= 1)
        acc += __shfl_down(acc, o, 64);
    __shared__ float wsum[4];
    int lane = threadIdx.x & 63;
    int wid  = threadIdx.x >> 6;
    if (lane == 0) wsum[wid] = acc;
    __syncthreads();
    if (wid == 0 && lane == 0)
        out[0] = (wsum[0] + wsum[1] + wsum[2] + wsum[3]) * INV_N;
}

extern "C" void kernel_launch(void* const* d_in, const int* in_sizes, int n_in,
                              void* d_out, int out_size, void* d_ws, size_t ws_size,
                              hipStream_t stream) {
    const float* depth = (const float*)d_in[0];
    const int* xA = (const int*)d_in[1];
    const int* yA = (const int*)d_in[2];
    const int* xB = (const int*)d_in[3];
    const int* yB = (const int*)d_in[4];
    const int* ord = (const int*)d_in[5];
    float* out = (float*)d_out;

    float* partials = (float*)d_ws;     // 256 floats
    rdc_kernel<<<NBLK, NT, 0, stream>>>(depth, xA, yA, xB, yB, ord, partials);
    rdc_finalize<<<1, 256, 0, stream>>>(partials, out, NBLK);
}

// Round 7
// 298.935 us; speedup vs baseline: 1.0752x; 1.0752x over previous
//
#include <hip/hip_runtime.h>

// relative_depth_crit — R6: R5's stripe-LDS gather, spill-free + pipelined.
// R5 failed on register spills (VGPR capped 128 by launch_bounds(512,2) vs
// ~200 needed -> scratch re-read every stripe) and serialized phases.
// Fixes: launch_bounds(512,1) (cap 512), zA/zB packed bf16 in one uint,
// register prefetch of stripe s+1 during scan of s, branchless clamped gathers.

constexpr int B = 64;
constexpr int H = 512;
constexpr int W = 640;
constexpr int P = 100000;
constexpr int SEGS = 4;                     // blocks per batch
constexpr int SEGP = P / SEGS;              // 25000 points per block
constexpr int NT = 512;                     // threads per block
constexpr int K = (SEGP + NT - 1) / NT;     // 49 points per thread
constexpr int TAIL_T = SEGP - (K - 1) * NT; // 424 valid threads at k=K-1
constexpr int SROWS = 48;                   // stripe rows
constexpr int NS = (H + SROWS - 1) / SROWS; // 11 stripes (last = 32 rows)
constexpr int SELEMS = SROWS * W;           // 30720 elems = 15 float4/thread
constexpr int LELEMS = (H - (NS - 1) * SROWS) * W;  // 20480 = 10 float4/thread
constexpr int PF = SELEMS / (NT * 4);       // 15
constexpr int PF_LAST = LELEMS / (NT * 4);  // 10
constexpr int NBLK = B * SEGS;              // 256
constexpr float INV_N = 1.0f / (float)(B * P);

typedef float vfloat4 __attribute__((ext_vector_type(4)));

__device__ __forceinline__ unsigned bf16_rnd(float f) {
    return (__builtin_bit_cast(unsigned, f) + 0x8000u) >> 16;
}

__global__ __launch_bounds__(NT, 1) void rdc_kernel(
        const float* __restrict__ depth,
        const int* __restrict__ xA, const int* __restrict__ yA,
        const int* __restrict__ xB, const int* __restrict__ yB,
        const int* __restrict__ ord,
        float* __restrict__ partials) {
    __shared__ unsigned short stripe[SELEMS];   // 61440 B
    __shared__ float wsum[8];

    int j = blockIdx.x;
    // XCD swizzle: all 4 segments of a batch on one XCD -> stripe HBM reads
    // amortized 4x through that XCD's L2.
    int x = j & 7;
    int g = j >> 3;                  // 0..31
    int b = (g >> 2) * 8 + x;        // batch
    int c = g & 3;                   // segment
    int t = threadIdx.x;

    const float* slab = depth + (size_t)b * (H * W);
    int base_pt = b * P + c * SEGP;

    // ---- phase 1: this thread's 49 points -> registers ----
    int offA[K], offB[K];
    unsigned zAB[K];                 // low16 = zA (bf16), high16 = zB (bf16)
    unsigned rankW[2] = {0u, 0u};    // bit k: ordinal != 1
    unsigned signW[2] = {0u, 0u};    // bit k: ordinal == 2
    #pragma unroll
    for (int k = 0; k < K; ++k) {
        int pl = k * NT + t;
        if (k == K - 1 && pl >= SEGP) pl = SEGP - 1;   // tail clamp (masked later)
        int gi = base_pt + pl;
        int xa = __builtin_nontemporal_load(&xA[gi]);
        int ya = __builtin_nontemporal_load(&yA[gi]);
        int xb = __builtin_nontemporal_load(&xB[gi]);
        int yb = __builtin_nontemporal_load(&yB[gi]);
        int od = __builtin_nontemporal_load(&ord[gi]);
        offA[k] = ya * W + xa;
        offB[k] = yb * W + xb;
        rankW[k >> 5] |= (unsigned)(od != 1) << (k & 31);
        signW[k >> 5] |= (unsigned)(od == 2) << (k & 31);
        zAB[k] = 0u;
    }

    // ---- prologue: stripe 0 -> LDS (bf16) ----
    vfloat4 pf[PF];
    #pragma unroll
    for (int i = 0; i < PF; ++i)
        pf[i] = *(const vfloat4*)(slab + ((i * NT + t) << 2));
    #pragma unroll
    for (int i = 0; i < PF; ++i) {
        uint2 pk;
        pk.x = bf16_rnd(pf[i].x) | (bf16_rnd(pf[i].y) << 16);
        pk.y = bf16_rnd(pf[i].z) | (bf16_rnd(pf[i].w) << 16);
        *(uint2*)&stripe[(i * NT + t) << 2] = pk;
    }
    __syncthreads();

    // ---- stripe loop: prefetch s+1 (regs) | scan s (LDS) | write s+1 ----
    for (int s = 0; s < NS; ++s) {
        int npf = 0;
        if (s + 1 < NS) {
            int gbase = (s + 1) * SELEMS;
            npf = (s + 1 == NS - 1) ? PF_LAST : PF;
            #pragma unroll
            for (int i = 0; i < PF; ++i)
                if (i < npf)
                    pf[i] = *(const vfloat4*)(slab + gbase + ((i * NT + t) << 2));
        }

        unsigned base = (unsigned)(s * SELEMS);
        unsigned span = (s == NS - 1) ? (unsigned)LELEMS : (unsigned)SELEMS;
        #pragma unroll
        for (int k = 0; k < K; ++k) {
            unsigned la = (unsigned)offA[k] - base;
            unsigned va = (unsigned)stripe[la < span ? la : 0u];
            zAB[k] = (la < span) ? ((zAB[k] & 0xFFFF0000u) | va) : zAB[k];
            unsigned lb = (unsigned)offB[k] - base;
            unsigned vb = (unsigned)stripe[lb < span ? lb : 0u];
            zAB[k] = (lb < span) ? ((zAB[k] & 0x0000FFFFu) | (vb << 16)) : zAB[k];
        }
        __syncthreads();          // all waves done reading buffer

        if (s + 1 < NS) {
            #pragma unroll
            for (int i = 0; i < PF; ++i)
                if (i < npf) {
                    uint2 pk;
                    pk.x = bf16_rnd(pf[i].x) | (bf16_rnd(pf[i].y) << 16);
                    pk.y = bf16_rnd(pf[i].z) | (bf16_rnd(pf[i].w) << 16);
                    *(uint2*)&stripe[(i * NT + t) << 2] = pk;
                }
            __syncthreads();      // buffer s+1 visible
        }
    }

    // ---- loss ----
    float tailf = (t < TAIL_T) ? 1.0f : 0.0f;
    float acc = 0.0f;
    #pragma unroll
    for (int k = 0; k < K; ++k) {
        float za = __builtin_bit_cast(float, zAB[k] << 16);
        float zb = __builtin_bit_cast(float, zAB[k] & 0xFFFF0000u);
        float zd = za - zb;
        unsigned rb = (rankW[k >> 5] >> (k & 31)) & 1u;
        unsigned sb = (signW[k >> 5] >> (k & 31)) & 1u;
        float gzd = sb ? zd : -zd;
        float lr = __logf(1.0f + __expf(-fminf(gzd, 1.0f)));
        float le = fmaxf(zd * zd, 1.0f);
        float l = rb ? lr : le;
        if (k == K - 1) l *= tailf;
        acc += l;
    }

    // ---- reduction (8 waves) ----
    #pragma unroll
    for (int o = 32; o > 0; o >>= 1)
        acc += __shfl_down(acc, o, 64);
    int lane = t & 63;
    int wid  = t >> 6;
    if (lane == 0) wsum[wid] = acc;
    __syncthreads();
    if (wid == 0 && lane == 0) {
        float v = 0.0f;
        #pragma unroll
        for (int w = 0; w < 8; ++w) v += wsum[w];
        partials[j] = v;
    }
}

__global__ __launch_bounds__(256) void rdc_finalize(
        const float* __restrict__ partials, float* __restrict__ out, int n) {
    float acc = 0.0f;
    for (int k = threadIdx.x; k < n; k += 256)
        acc += partials[k];
    #pragma unroll
    for (int o = 32; o > 0; o >>= 1)
        acc += __shfl_down(acc, o, 64);
    __shared__ float wsum[4];
    int lane = threadIdx.x & 63;
    int wid  = threadIdx.x >> 6;
    if (lane == 0) wsum[wid] = acc;
    __syncthreads();
    if (wid == 0 && lane == 0)
        out[0] = (wsum[0] + wsum[1] + wsum[2] + wsum[3]) * INV_N;
}

extern "C" void kernel_launch(void* const* d_in, const int* in_sizes, int n_in,
                              void* d_out, int out_size, void* d_ws, size_t ws_size,
                              hipStream_t stream) {
    const float* depth = (const float*)d_in[0];
    const int* xA = (const int*)d_in[1];
    const int* yA = (const int*)d_in[2];
    const int* xB = (const int*)d_in[3];
    const int* yB = (const int*)d_in[4];
    const int* ord = (const int*)d_in[5];
    float* out = (float*)d_out;

    float* partials = (float*)d_ws;     // 256 floats
    rdc_kernel<<<NBLK, NT, 0, stream>>>(depth, xA, yA, xB, yB, ord, partials);
    rdc_finalize<<<1, 256, 0, stream>>>(partials, out, NBLK);
}

// Round 8
// 293.524 us; speedup vs baseline: 1.0950x; 1.0184x over previous
//
#include <hip/hip_runtime.h>

// relative_depth_crit — R7: stripe-LDS gather, spill-PROOF version.
// R5/R6 failed on compiler choosing 128 VGPRs (heuristic; launch_bounds can't
// raise it) -> scratch spills (WRITE_SIZE 19.5MB). Fix:
//  (a) amdgpu_waves_per_eu(2,2) pins allocator budget to 512/2=256 VGPRs;
//  (b) state shrunk to ~170 regs: SEGS=8 (12500 pts/block), int4 index groups
//      (28 slots/thread), zA/zB packed bf16 in one u32.
// Scan: 11 bf16 stripes of 48 rows in 61KB LDS; 56 predicated ds_read_u16
// per thread per stripe; stripe s+1 prefetched into regs during scan of s.

constexpr int B = 64;
constexpr int H = 512;
constexpr int W = 640;
constexpr int P = 100000;
constexpr int SEGS = 8;                       // blocks per batch
constexpr int SEGP = P / SEGS;                // 12500 points per block
constexpr int NT = 512;
constexpr int G4 = SEGP / 4;                  // 3125 int4 groups per block
constexpr int KG = (G4 + NT - 1) / NT;        // 7 groups per thread
constexpr int TAIL_T = G4 - (KG - 1) * NT;    // 53 valid threads in last group
constexpr int KS = KG * 4;                    // 28 point slots per thread
constexpr int SROWS = 48;
constexpr int NS = (H + SROWS - 1) / SROWS;   // 11 stripes (last = 32 rows)
constexpr int SELEMS = SROWS * W;             // 30720 elems (61440 B bf16)
constexpr int LELEMS = (H - (NS - 1) * SROWS) * W;  // 20480
constexpr int PF = SELEMS / (NT * 4);         // 15 float4 per thread
constexpr int PF_LAST = LELEMS / (NT * 4);    // 10
constexpr int NBLK = B * SEGS;                // 512
constexpr float INV_N = 1.0f / (float)(B * P);

typedef float vfloat4 __attribute__((ext_vector_type(4)));
typedef int vint4 __attribute__((ext_vector_type(4)));

__device__ __forceinline__ unsigned bf16_rnd(float f) {
    return (__builtin_bit_cast(unsigned, f) + 0x8000u) >> 16;
}

__global__ __attribute__((amdgpu_flat_work_group_size(NT, NT),
                          amdgpu_waves_per_eu(2, 2)))
void rdc_kernel(
        const float* __restrict__ depth,
        const vint4* __restrict__ xA4, const vint4* __restrict__ yA4,
        const vint4* __restrict__ xB4, const vint4* __restrict__ yB4,
        const vint4* __restrict__ ord4,
        float* __restrict__ partials) {
    __shared__ unsigned short stripe[SELEMS];   // 61440 B
    __shared__ float wsum[8];

    int j = blockIdx.x;
    // XCD swizzle: x=j&7 ~ XCD; all 8 segments of a batch adjacent on one XCD
    // -> slab stripes fetched from HBM once, served 8x from that XCD's L2.
    int x = j & 7;
    int g = j >> 3;                  // 0..63
    int b = ((g >> 3) << 3) | x;     // batch
    int c = g & 7;                   // segment
    int t = threadIdx.x;

    const float* slab = depth + (size_t)b * (H * W);
    int base_i4 = (b * P + c * SEGP) >> 2;     // int4-granular base

    // ---- phase 1: 7 int4 index groups -> 28 point slots in registers ----
    int offA[KS], offB[KS];
    unsigned zAB[KS];                // low16 = zA bf16, high16 = zB bf16
    unsigned rankW = 0u;             // bit s: ordinal != 1
    unsigned signW = 0u;             // bit s: ordinal == 2
    #pragma unroll
    for (int k = 0; k < KG; ++k) {
        int gl = k * NT + t;
        if (k == KG - 1 && gl >= G4) gl = G4 - 1;   // tail clamp (masked later)
        int gi = base_i4 + gl;
        vint4 xa = __builtin_nontemporal_load(&xA4[gi]);
        vint4 ya = __builtin_nontemporal_load(&yA4[gi]);
        vint4 xb = __builtin_nontemporal_load(&xB4[gi]);
        vint4 yb = __builtin_nontemporal_load(&yB4[gi]);
        vint4 od = __builtin_nontemporal_load(&ord4[gi]);
        int s0 = 4 * k;
        offA[s0+0] = ya.x * W + xa.x;  offB[s0+0] = yb.x * W + xb.x;
        offA[s0+1] = ya.y * W + xa.y;  offB[s0+1] = yb.y * W + xb.y;
        offA[s0+2] = ya.z * W + xa.z;  offB[s0+2] = yb.z * W + xb.z;
        offA[s0+3] = ya.w * W + xa.w;  offB[s0+3] = yb.w * W + xb.w;
        rankW |= (unsigned)(od.x != 1) << (s0+0);
        rankW |= (unsigned)(od.y != 1) << (s0+1);
        rankW |= (unsigned)(od.z != 1) << (s0+2);
        rankW |= (unsigned)(od.w != 1) << (s0+3);
        signW |= (unsigned)(od.x == 2) << (s0+0);
        signW |= (unsigned)(od.y == 2) << (s0+1);
        signW |= (unsigned)(od.z == 2) << (s0+2);
        signW |= (unsigned)(od.w == 2) << (s0+3);
        zAB[s0+0] = 0u; zAB[s0+1] = 0u; zAB[s0+2] = 0u; zAB[s0+3] = 0u;
    }

    // ---- prologue: stage stripe 0 (fp32 -> bf16 -> LDS) ----
    vfloat4 pf[PF];
    #pragma unroll
    for (int i = 0; i < PF; ++i)
        pf[i] = *(const vfloat4*)(slab + ((i * NT + t) << 2));
    #pragma unroll
    for (int i = 0; i < PF; ++i) {
        uint2 pk;
        pk.x = bf16_rnd(pf[i].x) | (bf16_rnd(pf[i].y) << 16);
        pk.y = bf16_rnd(pf[i].z) | (bf16_rnd(pf[i].w) << 16);
        *(uint2*)&stripe[(i * NT + t) << 2] = pk;
    }
    __syncthreads();

    // ---- stripe loop: prefetch s+1 | scan s | write s+1 ----
    for (int s = 0; s < NS; ++s) {
        int npf = (s + 1 < NS) ? ((s + 1 == NS - 1) ? PF_LAST : PF) : 0;
        int gbase = (s + 1) * SELEMS;
        #pragma unroll
        for (int i = 0; i < PF; ++i)
            if (i < npf)
                pf[i] = *(const vfloat4*)(slab + gbase + ((i * NT + t) << 2));

        unsigned base = (unsigned)(s * SELEMS);
        unsigned span = (s == NS - 1) ? (unsigned)LELEMS : (unsigned)SELEMS;
        #pragma unroll
        for (int k = 0; k < KS; ++k) {
            unsigned la = (unsigned)offA[k] - base;
            unsigned va = (unsigned)stripe[la < span ? la : 0u];
            zAB[k] = (la < span) ? ((zAB[k] & 0xFFFF0000u) | va) : zAB[k];
            unsigned lb = (unsigned)offB[k] - base;
            unsigned vb = (unsigned)stripe[lb < span ? lb : 0u];
            zAB[k] = (lb < span) ? ((zAB[k] & 0x0000FFFFu) | (vb << 16)) : zAB[k];
        }
        __syncthreads();          // all waves done reading this stripe

        if (npf) {
            #pragma unroll
            for (int i = 0; i < PF; ++i)
                if (i < npf) {
                    uint2 pk;
                    pk.x = bf16_rnd(pf[i].x) | (bf16_rnd(pf[i].y) << 16);
                    pk.y = bf16_rnd(pf[i].z) | (bf16_rnd(pf[i].w) << 16);
                    *(uint2*)&stripe[(i * NT + t) << 2] = pk;
                }
            __syncthreads();      // stripe s+1 visible
        }
    }

    // ---- loss ----
    float acc = 0.0f;
    #pragma unroll
    for (int k = 0; k < KG; ++k) {
        float gmask = (k < KG - 1 || t < TAIL_T) ? 1.0f : 0.0f;
        #pragma unroll
        for (int m = 0; m < 4; ++m) {
            int s = 4 * k + m;
            float za = __builtin_bit_cast(float, zAB[s] << 16);
            float zb = __builtin_bit_cast(float, zAB[s] & 0xFFFF0000u);
            float zd = za - zb;
            unsigned rb = (rankW >> s) & 1u;
            unsigned sb = (signW >> s) & 1u;
            float gzd = sb ? zd : -zd;
            float lr = __logf(1.0f + __expf(-fminf(gzd, 1.0f)));
            float le = fmaxf(zd * zd, 1.0f);
            acc += gmask * (rb ? lr : le);
        }
    }

    // ---- reduction (8 waves) ----
    #pragma unroll
    for (int o = 32; o > 0; o >>= 1)
        acc += __shfl_down(acc, o, 64);
    int lane = t & 63;
    int wid  = t >> 6;
    if (lane == 0) wsum[wid] = acc;
    __syncthreads();
    if (wid == 0 && lane == 0) {
        float v = 0.0f;
        #pragma unroll
        for (int w = 0; w < 8; ++w) v += wsum[w];
        partials[j] = v;
    }
}

__global__ __launch_bounds__(256) void rdc_finalize(
        const float* __restrict__ partials, float* __restrict__ out, int n) {
    float acc = 0.0f;
    for (int k = threadIdx.x; k < n; k += 256)
        acc += partials[k];
    #pragma unroll
    for (int o = 32; o > 0; o >>= 1)
        acc += __shfl_down(acc, o, 64);
    __shared__ float wsum[4];
    int lane = threadIdx.x & 63;
    int wid  = threadIdx.x >> 6;
    if (lane == 0) wsum[wid] = acc;
    __syncthreads();
    if (wid == 0 && lane == 0)
        out[0] = (wsum[0] + wsum[1] + wsum[2] + wsum[3]) * INV_N;
}

extern "C" void kernel_launch(void* const* d_in, const int* in_sizes, int n_in,
                              void* d_out, int out_size, void* d_ws, size_t ws_size,
                              hipStream_t stream) {
    const float* depth = (const float*)d_in[0];
    const vint4* xA4 = (const vint4*)d_in[1];
    const vint4* yA4 = (const vint4*)d_in[2];
    const vint4* xB4 = (const vint4*)d_in[3];
    const vint4* yB4 = (const vint4*)d_in[4];
    const vint4* ord4 = (const vint4*)d_in[5];
    float* out = (float*)d_out;

    float* partials = (float*)d_ws;     // 512 floats
    rdc_kernel<<<NBLK, NT, 0, stream>>>(depth, xA4, yA4, xB4, yB4, ord4, partials);
    rdc_finalize<<<1, 256, 0, stream>>>(partials, out, NBLK);
}